// Round 17
// baseline (257.841 us; speedup 1.0000x reference)
//
#include <hip/hip_runtime.h>

#define SQ 4096
#define SKV 1024
#define BATCH 4
#define NH 8
#define DH 64
#define QD 1024
#define CD 768
#define INNER 512

typedef _Float16 half8 __attribute__((ext_vector_type(8)));
typedef _Float16 half4v __attribute__((ext_vector_type(4)));
typedef float floatx4 __attribute__((ext_vector_type(4)));
typedef float f32x16 __attribute__((ext_vector_type(16)));
typedef unsigned int uint4v __attribute__((ext_vector_type(4)));

#define MFMA16(a, b, c) __builtin_amdgcn_mfma_f32_16x16x32_f16(a, b, c, 0, 0, 0)
#define MFMA32(a, b, c) __builtin_amdgcn_mfma_f32_32x32x16_f16(a, b, c, 0, 0, 0)

// v_permlane32_swap_b32: a' = {a.lo31, b.lo31}, b' = {a.hi31, b.hi31}
#define PLSWAP(a, b) asm("v_permlane32_swap_b32 %0, %1" : "+v"(a), "+v"(b))

// async global->LDS, 16B per lane; LDS dest = wave-uniform base + lane*16
#define GLD16(gptr, lptr)                                                            \
  __builtin_amdgcn_global_load_lds(                                                  \
      (const __attribute__((address_space(1))) unsigned int*)(const void*)(gptr),    \
      (__attribute__((address_space(3))) unsigned int*)(void*)(lptr), 16, 0, 0)

// ---------------------------------------------------------------- prep (cast + transposes)
// (r13..r16-green form.) Blocks [0, NCAST) cast x/ctx fp32->fp16; blocks
// [NCAST, NCAST+4096) do the 4 weight transposes.
__global__ __launch_bounds__(256) void prep(const float* __restrict__ x,
                                            const float* __restrict__ ctx,
                                            const float* __restrict__ Wq,
                                            const float* __restrict__ Wk,
                                            const float* __restrict__ Wv,
                                            const float* __restrict__ Wo,
                                            _Float16* __restrict__ xh,
                                            _Float16* __restrict__ ctxh,
                                            _Float16* __restrict__ wqt,
                                            _Float16* __restrict__ wkvt,
                                            _Float16* __restrict__ wot) {
  __shared__ float tile[32][33];
  const size_t NX = (size_t)BATCH * SQ * QD;   // 16.7M (8192 blocks)
  const size_t NC = (size_t)BATCH * SKV * CD;  // 3.1M  (1536 blocks)
  const unsigned NCAST = (unsigned)((NX + NC) / 2048);

  if (blockIdx.x < NCAST) {  // -------- cast path
    size_t i = ((size_t)blockIdx.x * 256 + threadIdx.x) * 8;
    const float* s;
    _Float16* d;
    size_t off;
    if (i < NX) { s = x; d = xh; off = i; }
    else        { s = ctx; d = ctxh; off = i - NX; }
    floatx4 a = *(const floatx4*)(s + off);
    floatx4 b = *(const floatx4*)(s + off + 4);
    half8 h;
#pragma unroll
    for (int j = 0; j < 4; ++j) { h[j] = (_Float16)a[j]; h[4 + j] = (_Float16)b[j]; }
    *(half8*)(d + off) = h;
    return;
  }
  // -------- transpose path: src [R,C] fp32 -> dst [C,R] fp16
  const unsigned t = blockIdx.x - NCAST;
  const int z = t >> 10, rem = t & 1023;
  const float* src; _Float16* dst; int R, C;
  if (z == 0)      { src = Wq; dst = wqt;                        R = QD;    C = INNER; }
  else if (z == 1) { src = Wk; dst = wkvt;                       R = CD;    C = INNER; }
  else if (z == 2) { src = Wv; dst = wkvt + (size_t)INNER * CD;  R = CD;    C = INNER; }
  else             { src = Wo; dst = wot;                        R = INNER; C = QD;   }
  const int c0 = (rem & 31) * 32, r0 = (rem >> 5) * 32;
  if (c0 >= C || r0 >= R) return;
  const int tx = threadIdx.x & 31, ty = threadIdx.x >> 5;
#pragma unroll
  for (int i = 0; i < 32; i += 8)
    tile[ty + i][tx] = src[(size_t)(r0 + ty + i) * C + c0 + tx];
  __syncthreads();
#pragma unroll
  for (int i = 0; i < 32; i += 8)
    dst[(size_t)(c0 + ty + i) * R + r0 + tx] = (_Float16)tile[tx][ty + i];
}

// ---------------------------------------------------------------- 256x128 GEMM body
// (generalized from r16-green gemm_out — the first GEMM change that WON, -5us.)
// C[M,N] = A[M,K] @ Bt[N,K]^T, fp16 inputs. Tile 256x128, BK=32, 8 waves
// (512 thr, 4m x 2n of 64x64). Mechanism: step time is pinned by VMEM-instr
// issue (global_load_lds TA occupancy); 256-row tile stages 3 GLD16/thread for
// 2x the output area of the old 128-tile's 4 -> 25% fewer staged bytes/output.
// Ring-3 counted vmcnt: {vmcnt(3) -> s_barrier -> stage(t+2) -> compute}; never
// vmcnt(0) in-loop. T2 swizzle: src blk ^= (row>>1)&3 (invariant under +128/+256
// row offsets), reads apply quad^r2. LDS 72 KB -> 2 blocks/CU.
// MODE 2: fp32 + bias. MODE 3: fp16 out scaled by 0.125*log2(e).
// MODE 4: merged k/v epilogue — n<512 -> kh row-major; n>=512 -> vT scatter
//   (256-row tiles don't straddle batch boundaries: 256 | 1024).
template <int MODE, int K, int N>
__device__ __forceinline__ void gemm256_body(const _Float16* __restrict__ A,
                                             const _Float16* __restrict__ Bt,
                                             void* __restrict__ Cout,
                                             void* __restrict__ Cout2,
                                             const float* __restrict__ bias,
                                             int bx, int by,
                                             _Float16* As16, _Float16* Bs) {
  const int tid = threadIdx.x;
  const int wave = tid >> 6, lane = tid & 63;
  const int quad = lane >> 4, l16 = lane & 15;
  const int wm = (wave >> 1) * 64, wn = (wave & 1) * 64;  // wm 0..192, wn 0..64
  const size_t n0 = (size_t)bx * 128, m0 = (size_t)by * 256;

  floatx4 acc[4][4] = {};

  // staging: 512 threads; A rows tid>>2 (+128 for 2nd GLD16), B rows tid>>2.
  const int r4 = tid >> 2, b4 = (tid & 3) ^ ((r4 >> 1) & 3);
  const _Float16* ag = A + (m0 + r4) * (size_t)K + b4 * 8;
  const _Float16* bg = Bt + (n0 + r4) * (size_t)K + b4 * 8;

#define GSTAGE2(bi, k0)                                                    \
  do {                                                                     \
    GLD16(ag + (k0), As16 + (bi)*8192 + tid * 8);                          \
    GLD16(ag + (k0) + (size_t)128 * K, As16 + (bi)*8192 + tid * 8 + 4096); \
    GLD16(bg + (k0), Bs + (bi)*4096 + tid * 8);                            \
  } while (0)

  constexpr int NT = K / 32;
  GSTAGE2(0, 0);
  GSTAGE2(1, 32);
  int cb = 0;
#pragma unroll 2
  for (int t = 0; t < NT; ++t) {
    if (t + 1 < NT)
      asm volatile("s_waitcnt vmcnt(3)" ::: "memory");  // tile t landed; t+1 flying
    else
      asm volatile("s_waitcnt vmcnt(0)" ::: "memory");  // final tile
    __builtin_amdgcn_sched_barrier(0);
    __builtin_amdgcn_s_barrier();  // tile t visible; buf (t+2)%3 free
    __builtin_amdgcn_sched_barrier(0);
    if (t + 2 < NT) {
      int nb = cb + 2; if (nb >= 3) nb -= 3;
      GSTAGE2(nb, (t + 2) * 32);
    }
    const _Float16* as = As16 + cb * 8192;
    const _Float16* bs = Bs + cb * 4096;

    const int r2 = (l16 >> 1) & 3;
    half8 af[4], bf[4];
#pragma unroll
    for (int mt = 0; mt < 4; ++mt)
      af[mt] = *(const half8*)(as + (wm + mt * 16 + l16) * 32 + (quad ^ r2) * 8);
#pragma unroll
    for (int nt = 0; nt < 4; ++nt)
      bf[nt] = *(const half8*)(bs + (wn + nt * 16 + l16) * 32 + (quad ^ r2) * 8);
    __builtin_amdgcn_s_setprio(1);
#pragma unroll
    for (int mt = 0; mt < 4; ++mt)
#pragma unroll
      for (int nt = 0; nt < 4; ++nt)
        acc[mt][nt] = MFMA16(af[mt], bf[nt], acc[mt][nt]);
    __builtin_amdgcn_s_setprio(0);
    cb = (cb == 2) ? 0 : cb + 1;
  }
#undef GSTAGE2

  // epilogue: C/D layout row = quad*4+r, col = l16  (green forms; wm spans 256)
  if (MODE == 3) {
    _Float16* C = (_Float16*)Cout;
    const float sc = 0.125f * 1.44269504088896f;
#pragma unroll
    for (int mt = 0; mt < 4; ++mt) {
      const size_t row = m0 + wm + mt * 16 + quad * 4;
#pragma unroll
      for (int nt = 0; nt < 4; ++nt) {
        const size_t col = n0 + wn + nt * 16 + l16;
#pragma unroll
        for (int r = 0; r < 4; ++r)
          C[(row + r) * N + col] = (_Float16)(acc[mt][nt][r] * sc);
      }
    }
  } else if (MODE == 4) {
    if (n0 < INNER) {  // K half: row-major [M, INNER]
      _Float16* C = (_Float16*)Cout;
#pragma unroll
      for (int mt = 0; mt < 4; ++mt) {
        const size_t row = m0 + wm + mt * 16 + quad * 4;
#pragma unroll
        for (int nt = 0; nt < 4; ++nt) {
          const size_t col = n0 + wn + nt * 16 + l16;
#pragma unroll
          for (int r = 0; r < 4; ++r)
            C[(row + r) * INNER + col] = (_Float16)acc[mt][nt][r];
        }
      }
    } else {  // V half: scatter to vT[b][h][d][kv]
      _Float16* C = (_Float16*)Cout2;
      const int b = (int)(m0 >> 10);
#pragma unroll
      for (int mt = 0; mt < 4; ++mt) {
        const int kvb = (int)(m0 & 1023) + wm + mt * 16 + quad * 4;
#pragma unroll
        for (int nt = 0; nt < 4; ++nt) {
          const int col = (int)(n0 - INNER + wn + nt * 16 + l16);
          const int h = col >> 6, d = col & 63;
          half4v pk;
#pragma unroll
          for (int r = 0; r < 4; ++r) pk[r] = (_Float16)acc[mt][nt][r];
          *(half4v*)(C + (size_t)((b * NH + h) * DH + d) * SKV + kvb) = pk;
        }
      }
    }
  } else {
    float* C = (float*)Cout;
#pragma unroll
    for (int mt = 0; mt < 4; ++mt) {
      const size_t row = m0 + wm + mt * 16 + quad * 4;
#pragma unroll
      for (int nt = 0; nt < 4; ++nt) {
        const size_t col = n0 + wn + nt * 16 + l16;
        const float bb = bias[col];
#pragma unroll
        for (int r = 0; r < 4; ++r)
          C[(row + r) * N + col] = acc[mt][nt][r] + bb;
      }
    }
  }
}

// ---------------------------------------------------------------- fused projections
// THIS ROUND: 256x128 tiles (r16's winning lever applied to the bigger GEMM pair).
// Q-proj: 64 m-stripes x 4 n = 256 blocks; KV-proj: 16 x 8 = 128 -> 384 blocks
// at 512 thr, 72 KB LDS -> 2 blocks/CU capacity (512 slots): all resident.
// XCD-local: per xcd, 48 blocks = 32 Q + 16 KV, mod-3 interleaved {Q,Q,KV}.
// Bijective per xcd: jq = 2*(j/3)+seg covers 0..31 -> (jq&3, xcd*8+(jq>>2));
// jkv = j/3 covers 0..15 -> (jkv&7, xcd*2+(jkv>>3)). Disjoint m-bands per xcd.
__global__ __launch_bounds__(512) void proj_fused(const _Float16* __restrict__ xh,
                                                  const _Float16* __restrict__ ctxh,
                                                  const _Float16* __restrict__ wqt,
                                                  const _Float16* __restrict__ wkvt,
                                                  _Float16* __restrict__ qh,
                                                  _Float16* __restrict__ kh,
                                                  _Float16* __restrict__ vth) {
  __shared__ _Float16 As16[3 * 256 * 32];  // 48 KB
  __shared__ _Float16 Bs[3 * 128 * 32];    // 24 KB
  const int b = blockIdx.x;
  const int xcd = b & 7, j = b >> 3;  // j: 0..47
  const int seg = j % 3;
  if (seg == 2) {  // KV: M=4096, N=1024 (k|v), K=768
    const int jkv = j / 3;  // 0..15
    gemm256_body<4, CD, 2 * INNER>(ctxh, wkvt, kh, vth, nullptr,
                                   jkv & 7, xcd * 2 + (jkv >> 3), As16, Bs);
  } else {  // Q: M=16384, N=512, K=1024 (scale folded)
    const int jq = (j / 3) * 2 + seg;  // 0..31
    gemm256_body<3, QD, INNER>(xh, wqt, qh, nullptr, nullptr,
                               jq & 3, xcd * 8 + (jq >> 2), As16, Bs);
  }
}

// ---------------------------------------------------------------- output projection
// (r16-green, unchanged.) 512 blocks x 512 thr = exact 2/CU, 256x128 tile.
// XCD-local: xcd owns aoh m-stripes [xcd*8, xcd*8+8).
__global__ __launch_bounds__(512) void gemm_out(const _Float16* __restrict__ A,
                                                const _Float16* __restrict__ Bt,
                                                float* __restrict__ Cout,
                                                const float* __restrict__ bias) {
  __shared__ _Float16 As16[3 * 256 * 32];  // 48 KB
  __shared__ _Float16 Bs[3 * 128 * 32];    // 24 KB
  const int b = blockIdx.x;
  const int xcd = b & 7, i = b >> 3;  // i: 0..63
  gemm256_body<2, INNER, QD>(A, Bt, Cout, nullptr, bias,
                             i & 7, xcd * 8 + (i >> 3), As16, Bs);
}

// ---------------------------------------------------------------- flash attention v8
// (byte-identical to r14/r15/r16-green.) 32x32x16 MFMA. Swapped QK^T (S^T = K·Q^T):
// lane owns one q-row, softmax lane-local; P->PV-A transpose = 4 permlane32_swap;
// row-sums via ones-MFMA (same layout as o -> lane-local normalize). KV-tile 64,
// double-buffered LDS, one barrier per tile, prefetch-before-compute. XOR-swizzled
// tiles (blk ^= row&7) with pre-swizzled global source. Grid 1024, XCD swizzle.
// exp path: __builtin_exp2f ONLY (amdgcn builtin and raw asm both red r7/r9 —
// mechanism unresolved, change banned). No setprio (A/B: +3us, lockstep waves).
__global__ __launch_bounds__(256, 4) void flash_attn8(const _Float16* __restrict__ Q,
                                                      const _Float16* __restrict__ Kp,
                                                      const _Float16* __restrict__ Vt,
                                                      _Float16* __restrict__ O) {
  __shared__ _Float16 Ksb[2 * 64 * 64];  // [buf][kv64][d64], 16B-blk XOR by kv&7
  __shared__ _Float16 Vsb[2 * 64 * 64];  // [buf][d64][kv64], 16B-blk XOR by d&7
  const int tid = threadIdx.x;
  const int wave = tid >> 6, lane = tid & 63;
  const int l31 = lane & 31, hi = lane >> 5, x7 = lane & 7;

  // XCD-aware swizzle: 1024 blocks % 8 == 0 -> bijective chunked remap
  const int flat = blockIdx.x;
  const int nf = (flat & 7) * 128 + (flat >> 3);
  const int qblk = nf & 31, bh = nf >> 5;
  const int b = bh >> 3, h = bh & 7;

  const size_t qrow0 = (size_t)b * SQ + qblk * 128 + wave * 32;
  const _Float16* qptr = Q + qrow0 * INNER + h * DH;
  const _Float16* kbase = Kp + (size_t)b * SKV * INNER + h * DH;
  const _Float16* vbase = Vt + (size_t)bh * DH * SKV;

  // staging: linear LDS dest (tid*16B), pre-swizzled global src (blk ^= row&7)
  const int kr = tid >> 3;
  const int kb = (tid & 7) ^ (kr & 7);
  const _Float16* kg = kbase + (size_t)kr * INNER + kb * 8;
  const _Float16* vg = vbase + (size_t)kr * SKV + kb * 8;

#define STAGE_KV(bi, tt)                                                        \
  do {                                                                          \
    _Float16* _kl = Ksb + (bi) * 4096 + tid * 8;                                \
    _Float16* _vl = Vsb + (bi) * 4096 + tid * 8;                                \
    GLD16(kg + (size_t)((tt) * 64) * INNER, _kl);                               \
    GLD16(kg + (size_t)((tt) * 64 + 32) * INNER, _kl + 2048);                   \
    GLD16(vg + (tt) * 64, _vl);                                                 \
    GLD16(vg + (size_t)32 * SKV + (tt) * 64, _vl + 2048);                       \
  } while (0)

  half8 aq[4];
#pragma unroll
  for (int i = 0; i < 4; ++i)
    aq[i] = *(const half8*)(qptr + (size_t)l31 * INNER + i * 16 + hi * 8);

  int koff[4], voffB[4];
#pragma unroll
  for (int i = 0; i < 4; ++i)
    koff[i] = l31 * 64 + (((i * 2 + hi) ^ x7) << 3);
#pragma unroll
  for (int j = 0; j < 4; ++j)
    voffB[j] = l31 * 64 + (((j * 2 + hi) ^ x7) << 3);

  half8 ones;
#pragma unroll
  for (int j = 0; j < 8; ++j) ones[j] = (_Float16)1.0f;

  f32x16 o0 = {}, o1 = {}, osum = {};

  STAGE_KV(0, 0);

  for (int t = 0; t < SKV / 64; ++t) {
    __syncthreads();
    if (t < SKV / 64 - 1) STAGE_KV((t + 1) & 1, t + 1);
    const _Float16* ks = Ksb + (t & 1) * 4096;
    const _Float16* vs = Vsb + (t & 1) * 4096;

#pragma unroll
    for (int c2 = 0; c2 < 2; ++c2) {
      half8 ak[4];
#pragma unroll
      for (int i = 0; i < 4; ++i)
        ak[i] = *(const half8*)(ks + c2 * 2048 + koff[i]);

      f32x16 st = {};
#pragma unroll
      for (int i = 0; i < 4; ++i) st = MFMA32(ak[i], aq[i], st);

      unsigned w[8];
#pragma unroll
      for (int j = 0; j < 8; ++j) {
        float plo = __builtin_exp2f(st[2 * j]);
        float phi = __builtin_exp2f(st[2 * j + 1]);
        w[j] = __builtin_bit_cast(unsigned, __builtin_amdgcn_cvt_pkrtz(plo, phi));
      }
      PLSWAP(w[0], w[2]);
      PLSWAP(w[1], w[3]);
      PLSWAP(w[4], w[6]);
      PLSWAP(w[5], w[7]);
      uint4v u0 = {w[0], w[1], w[2], w[3]};
      uint4v u1 = {w[4], w[5], w[6], w[7]};
      half8 A0 = __builtin_bit_cast(half8, u0);
      half8 A1 = __builtin_bit_cast(half8, u1);

      osum = MFMA32(A0, ones, osum);
      osum = MFMA32(A1, ones, osum);

      {
        half8 bv00 = *(const half8*)(vs + 0 * 2048 + voffB[c2 * 2 + 0]);
        half8 bv10 = *(const half8*)(vs + 1 * 2048 + voffB[c2 * 2 + 0]);
        o0 = MFMA32(A0, bv00, o0);
        o1 = MFMA32(A0, bv10, o1);
        half8 bv01 = *(const half8*)(vs + 0 * 2048 + voffB[c2 * 2 + 1]);
        half8 bv11 = *(const half8*)(vs + 1 * 2048 + voffB[c2 * 2 + 1]);
        o0 = MFMA32(A1, bv01, o0);
        o1 = MFMA32(A1, bv11, o1);
      }
    }
  }

  float inv16[16];
#pragma unroll
  for (int r = 0; r < 16; ++r) inv16[r] = 1.0f / osum[r];

  _Float16* op = O + qrow0 * INNER + h * DH;
#pragma unroll
  for (int r = 0; r < 16; ++r) {
    const int q = (r & 3) + 8 * (r >> 2) + 4 * hi;
    op[(size_t)q * INNER + l31] = (_Float16)(o0[r] * inv16[r]);
    op[(size_t)q * INNER + 32 + l31] = (_Float16)(o1[r] * inv16[r]);
  }
#undef STAGE_KV
}

// ---------------------------------------------------------------- launcher
extern "C" void kernel_launch(void* const* d_in, const int* in_sizes, int n_in,
                              void* d_out, int out_size, void* d_ws, size_t ws_size,
                              hipStream_t stream) {
  const float* x   = (const float*)d_in[0];
  const float* ctx = (const float*)d_in[1];
  const float* Wq  = (const float*)d_in[2];
  const float* Wk  = (const float*)d_in[3];
  const float* Wv  = (const float*)d_in[4];
  const float* Wo  = (const float*)d_in[5];
  const float* bo  = (const float*)d_in[6];
  float* out = (float*)d_out;

  const size_t NX = (size_t)BATCH * SQ * QD;   // 16.7M
  const size_t NC = (size_t)BATCH * SKV * CD;  // 3.1M

  _Float16* ws = (_Float16*)d_ws;
  _Float16* xh   = ws;                                   // [16384,1024] fp16
  _Float16* ctxh = xh + NX;                              // [4096,768]
  _Float16* wqt  = ctxh + NC;                            // [512,1024]
  _Float16* wkvt = wqt + (size_t)INNER * QD;             // [1024,768] (k rows, then v)
  _Float16* wot  = wkvt + (size_t)2 * INNER * CD;        // [1024,512]
  _Float16* qh   = wot + (size_t)QD * INNER;             // [16384,512]
  _Float16* kh   = qh + (size_t)BATCH * SQ * INNER;      // [4096,512]
  _Float16* vth  = kh + (size_t)BATCH * SKV * INNER;     // [4,8,64,1024]
  _Float16* aoh  = xh;  // alias: xh dead after proj_fused; aoh (8.4M) fits in NX

  // cast (9728 blocks) + weight transposes (4096 blocks) in one launch
  prep<<<dim3((unsigned)((NX + NC) / 2048) + 4096), 256, 0, stream>>>(
      x, ctx, Wq, Wk, Wv, Wo, xh, ctxh, wqt, wkvt, wot);

  // fused Q + KV projections (384 blocks x 512 thr, 256x128 tiles, XCD-local)
  proj_fused<<<dim3(384), 512, 0, stream>>>(xh, ctxh, wqt, wkvt, qh, kh, vth);

  // attention (1024 blocks, zero tail)
  flash_attn8<<<dim3(BATCH * NH * SQ / 128), 256, 0, stream>>>(qh, kh, vth, aoh);

  // output projection + bias, fp32 out (512 blocks x 512 thr = exact 2/CU, 256x128)
  gemm_out<<<dim3(512), 512, 0, stream>>>(aoh, wot, out, bo);
}